// Round 4
// baseline (2868.550 us; speedup 1.0000x reference)
//
#include <hip/hip_runtime.h>
#include <hip/hip_bf16.h>

// CrystalGraphConvNet forward, MI355X. All tensors FLOAT32.
// d_out = [out(2000), x(6.4M)] float32.
//
// Decomposition: gated = S[i] + T[nbr_idx[i,j]] + e_ij @ W_edge, with
// S = x@W[0:64]+b, T = x@W[64:128] precomputed per atom per layer.
// BN over batch => stats pass (stores gated, 614MB) + streaming apply pass.
//
// R8 change: edge_stats_store splits channel halves across wave pairs.
// R7 evidence: VGPR=56 < 82 named weights => AGPR spill persists; per-edge
// instr model (82 fma + 82 accvgpr_read + 41 readlane + misc = 440 cyc) predicts
// 215us VALU issue vs 210us measured (0.49 x 429). Fix: 41 weights/wave (waves
// 0,2 = lo channels, 1,3 = hi; 16 atoms each), pinned ONCE outside loops (R5's
// pins were inside the atom loop => 8x reloads => catastrophe). ~75 VGPR live
// => ~6 waves/SIMD, no accvgpr tax. gated layout now planar [edge][128].

#define NA    100000
#define MN    12
#define NC    2000
#define ORIGF 92
#define NBRF  41
#define FD    64
#define NBLK  3125     // edge-kernel blocks: 3125 * 32 atoms = 100000 exactly
#define EPSF  1e-5f

#define REP28(X) X(0)X(1)X(2)X(3)X(4)X(5)X(6)X(7)X(8)X(9)X(10)X(11)X(12)X(13)X(14)X(15)X(16)X(17)X(18)X(19)X(20)X(21)X(22)X(23)X(24)X(25)X(26)X(27)
#define REP41(X) X(0)X(1)X(2)X(3)X(4)X(5)X(6)X(7)X(8)X(9)X(10)X(11)X(12)X(13)X(14)X(15)X(16)X(17)X(18)X(19)X(20)X(21)X(22)X(23)X(24)X(25)X(26)X(27)X(28)X(29)X(30)X(31)X(32)X(33)X(34)X(35)X(36)X(37)X(38)X(39)X(40)
#define REP64(X) X(0)X(1)X(2)X(3)X(4)X(5)X(6)X(7)X(8)X(9)X(10)X(11)X(12)X(13)X(14)X(15)X(16)X(17)X(18)X(19)X(20)X(21)X(22)X(23)X(24)X(25)X(26)X(27)X(28)X(29)X(30)X(31)X(32)X(33)X(34)X(35)X(36)X(37)X(38)X(39)X(40)X(41)X(42)X(43)X(44)X(45)X(46)X(47)X(48)X(49)X(50)X(51)X(52)X(53)X(54)X(55)X(56)X(57)X(58)X(59)X(60)X(61)X(62)X(63)

typedef const float* fp;

__device__ __forceinline__ float rlf(float v, int q){
  return __int_as_float(__builtin_amdgcn_readlane(__float_as_int(v), q));
}
__device__ __forceinline__ float fsig(float z){
  z = fminf(fmaxf(z, -30.f), 30.f);
  return 1.f / (1.f + __expf(-z));
}
__device__ __forceinline__ float ftanh(float z){
  z = fminf(fmaxf(z, -15.f), 15.f);
  float e = __expf(2.f * z);
  return (e - 1.f) / (e + 1.f);
}

// ---------------- zero scratch ----------------
__global__ void zero_kernel(float* __restrict__ p, int n){
  for (int i = blockIdx.x * blockDim.x + threadIdx.x; i < n; i += gridDim.x * blockDim.x)
    p[i] = 0.f;
}

// ---------------- embedding: x = atom_fea @ emb_W + emb_b ----------------
__global__ __launch_bounds__(256, 2) void emb_kernel(
    fp __restrict__ af, fp __restrict__ W, fp __restrict__ b,
    float* __restrict__ x)
{
  const int lane = threadIdx.x & 63, w = threadIdx.x >> 6;
#define EA(k) float wa##k = W[k * FD + lane];
  REP64(EA)
#undef EA
#define EB(k) float wb##k = W[(k + 64) * FD + lane];
  REP28(EB)
#undef EB
  const float bias = b[lane];
  const int base = blockIdx.x * 32 + w * 8;
  #pragma unroll 1
  for (int it = 0; it < 8; ++it){
    const int i = base + it;
    float ev0 = af[i * ORIGF + lane];
    float ev1 = (lane < 28) ? af[i * ORIGF + 64 + lane] : 0.f;
    float acc = bias;
#define FA(k) acc = fmaf(rlf(ev0, k), wa##k, acc);
    REP64(FA)
#undef FA
#define FB(k) acc = fmaf(rlf(ev1, k), wb##k, acc);
    REP28(FB)
#undef FB
    x[i * FD + lane] = acc;
  }
}

// ---------------- stw: out[N][128] = xin[N][64] @ W[64][128] (+bias) ----------------
__global__ __launch_bounds__(256, 4) void stw_kernel(
    const float* __restrict__ xin, fp __restrict__ W, fp __restrict__ bias,
    float* __restrict__ out)
{
  const int lane = threadIdx.x & 63, w = threadIdx.x >> 6;
  const int ch = (w & 1) * 64 + lane;
#define SW(k) float wv##k = W[k * 128 + ch];
  REP64(SW)
#undef SW
  const float bb = bias ? bias[ch] : 0.f;
  const int base = blockIdx.x * 32 + (w >> 1) * 16;
  #pragma unroll 1
  for (int it = 0; it < 16; ++it){
    const int i = base + it;
    float xv = xin[i * FD + lane];
    float acc = bb;
#define SF(k) acc = fmaf(rlf(xv, k), wv##k, acc);
    REP64(SF)
#undef SF
    out[i * 128 + ch] = acc;
  }
}

// ---------------- edge stats (fallback: no store) ----------------
__global__ __launch_bounds__(256, 2) void edge_stats_kernel(
    const float* __restrict__ S, const float* __restrict__ T,
    fp __restrict__ nbr, const int* __restrict__ idx,
    fp __restrict__ We, float* __restrict__ p1)   // p1: [NBLK][256] coalesced
{
  const int lane = threadIdx.x & 63, w = threadIdx.x >> 6;
  const int clo = lane, chi = lane + 64;
#define DW(q) float wlo##q = We[q * 128 + clo], whi##q = We[q * 128 + chi];
  REP41(DW)
#undef DW
  float sum_lo = 0.f, ssq_lo = 0.f, sum_hi = 0.f, ssq_hi = 0.f;
  const int base = blockIdx.x * 32 + w * 8;
  #pragma unroll 1
  for (int it = 0; it < 8; ++it){
    const int i = base + it;
    const float slo = S[i * 128 + clo];
    const float shi = S[i * 128 + chi];
    int kk = (lane < MN) ? idx[i * MN + lane] : 0;
    fp nb = nbr + (size_t)i * (MN * NBRF);
    int k0 = __builtin_amdgcn_readlane(kk, 0);
    float tlo = T[k0 * 128 + clo];
    float thi = T[k0 * 128 + chi];
    float ev  = (lane < NBRF) ? nb[lane] : 0.f;
    #pragma unroll 1
    for (int j = 0; j < MN; j++){
      float tlo_n = 0.f, thi_n = 0.f, ev_n = 0.f;
      if (j + 1 < MN){
        int kn = __builtin_amdgcn_readlane(kk, j + 1);
        tlo_n = T[kn * 128 + clo];
        thi_n = T[kn * 128 + chi];
        ev_n  = (lane < NBRF) ? nb[(j + 1) * NBRF + lane] : 0.f;
      }
      float glo = slo + tlo, ghi = shi + thi;
#define EF(q) { float s_ = rlf(ev, q); glo = fmaf(s_, wlo##q, glo); ghi = fmaf(s_, whi##q, ghi); }
      REP41(EF)
#undef EF
      sum_lo += glo; ssq_lo = fmaf(glo, glo, ssq_lo);
      sum_hi += ghi; ssq_hi = fmaf(ghi, ghi, ssq_hi);
      tlo = tlo_n; thi = thi_n; ev = ev_n;
    }
  }
  __shared__ float red[4 * 512];
  red[w * 512 + 2 * clo    ] = sum_lo;
  red[w * 512 + 2 * clo + 1] = ssq_lo;
  red[w * 512 + 2 * chi    ] = sum_hi;
  red[w * 512 + 2 * chi + 1] = ssq_hi;
  __syncthreads();
  const int t = threadIdx.x;            // stat id: (t>>7)*128 channels = sum|ssq
  const int ch = t & 127, which = t >> 7;
  float v = 0.f;
  #pragma unroll
  for (int ww = 0; ww < 4; ++ww) v += red[ww * 512 + 2 * ch + which];
  p1[blockIdx.x * 256 + t] = v;
}

// ---------------- edge stats + gated store (big-ws path, R8 wave-split) ----------------
// Waves 0,2: channels 0..63; waves 1,3: channels 64..127. Wave pair (w>>1)
// covers 16 atoms; block = 32 atoms. gated layout PLANAR: [edge][128],
// each wave stores its contiguous 64-float half (coalesced 256B).
__global__ __launch_bounds__(256, 4) void edge_stats_store_kernel(
    const float* __restrict__ S, const float* __restrict__ T,
    fp __restrict__ nbr, const int* __restrict__ idx,
    fp __restrict__ We, float* __restrict__ p1, float* __restrict__ gated)
{
  const int lane = threadIdx.x & 63, w = threadIdx.x >> 6;
  const int half = w & 1;
  const int ch = half * 64 + lane;
#define DW(q) float wv##q = We[q * 128 + ch];
  REP41(DW)
#undef DW
#define PIN(q) asm volatile("" : "+v"(wv##q));
  REP41(PIN)     // single pin point, OUTSIDE all loops
#undef PIN
  float sum = 0.f, ssq = 0.f;
  const int base = blockIdx.x * 32 + (w >> 1) * 16;
  #pragma unroll 1
  for (int it = 0; it < 16; ++it){
    const int i = base + it;
    const float sv = S[i * 128 + ch];
    int kk = (lane < MN) ? idx[i * MN + lane] : 0;
    fp nb = nbr + (size_t)i * (MN * NBRF);
    float* gb = gated + (((size_t)i * MN) << 7) + ch;
    int k0 = __builtin_amdgcn_readlane(kk, 0);
    float tv = T[k0 * 128 + ch];
    float ev = (lane < NBRF) ? nb[lane] : 0.f;
    #pragma unroll 1
    for (int j = 0; j < MN; j++){
      float tv_n = 0.f, ev_n = 0.f;
      if (j + 1 < MN){
        int kn = __builtin_amdgcn_readlane(kk, j + 1);
        tv_n = T[kn * 128 + ch];
        ev_n = (lane < NBRF) ? nb[(j + 1) * NBRF + lane] : 0.f;
      }
      float g = sv + tv;
#define EF(q) g = fmaf(rlf(ev, q), wv##q, g);
      REP41(EF)
#undef EF
      gb[(size_t)j << 7] = g;
      sum += g; ssq = fmaf(g, g, ssq);
      tv = tv_n; ev = ev_n;
    }
  }
  // per-block stats: wave w holds 64 channels (half = w&1); combine waves h, h+2
  __shared__ float red[4 * 128];
  red[w * 128 + 2 * lane    ] = sum;
  red[w * 128 + 2 * lane + 1] = ssq;
  __syncthreads();
  const int t = threadIdx.x;            // t<256: which = t>>7, c = t&127 (as before)
  const int c = t & 127, which = t >> 7;
  const int h = c >> 6, cl = c & 63;
  float v = red[h * 128 + 2 * cl + which] + red[(h + 2) * 128 + 2 * cl + which];
  p1[blockIdx.x * 256 + t] = v;
}

// ---------------- edge apply from stored gated (big-ws path) ----------------
// Pure stream: planar gated [edge][128]; BN1 affine, sig*tanh, sum_j.
__global__ __launch_bounds__(256, 4) void edge_apply_load_kernel(
    const float* __restrict__ gated, const float* __restrict__ ss1,
    float* __restrict__ ns, float* __restrict__ p2)   // p2: [NBLK][128]
{
  const int lane = threadIdx.x & 63, w = threadIdx.x >> 6;
  const float sc_lo = ss1[lane],      sh_lo = ss1[128 + lane];
  const float sc_hi = ss1[64 + lane], sh_hi = ss1[192 + lane];
  float sum2 = 0.f, ssq2 = 0.f;
  const int base = blockIdx.x * 32 + w * 8;
  #pragma unroll 1
  for (int it = 0; it < 8; ++it){
    const int i = base + it;
    fp gb = gated + (((size_t)i * MN) << 7);
    float acc = 0.f;
    #pragma unroll
    for (int j = 0; j < MN; ++j){
      float glo = gb[(j << 7) + lane];
      float ghi = gb[(j << 7) + 64 + lane];
      float filt = fsig(fmaf(glo, sc_lo, sh_lo));
      float core = ftanh(fmaf(ghi, sc_hi, sh_hi));
      acc = fmaf(filt, core, acc);
    }
    ns[i * FD + lane] = acc;
    sum2 += acc; ssq2 = fmaf(acc, acc, ssq2);
  }
  __shared__ float red[4 * 128];
  red[w * 128 + 2 * lane    ] = sum2;
  red[w * 128 + 2 * lane + 1] = ssq2;
  __syncthreads();
  const int t = threadIdx.x;
  if (t < 128){
    const int ch = t & 63, which = t >> 6;
    float v = 0.f;
    #pragma unroll
    for (int ww = 0; ww < 4; ++ww) v += red[ww * 128 + 2 * ch + which];
    p2[blockIdx.x * 128 + t] = v;
  }
}

// ---------------- edge apply (fallback: recompute) ----------------
__global__ __launch_bounds__(256, 2) void edge_apply_kernel(
    const float* __restrict__ S, const float* __restrict__ T,
    fp __restrict__ nbr, const int* __restrict__ idx,
    fp __restrict__ We, const float* __restrict__ ss1,
    float* __restrict__ ns, float* __restrict__ p2)   // p2: [NBLK][128]
{
  const int lane = threadIdx.x & 63, w = threadIdx.x >> 6;
  const int clo = lane, chi = lane + 64;
#define DW(q) float wlo##q = We[q * 128 + clo], whi##q = We[q * 128 + chi];
  REP41(DW)
#undef DW
  const float sc_lo = ss1[clo],       sh_lo = ss1[128 + clo];
  const float sc_hi = ss1[chi],       sh_hi = ss1[128 + chi];
  float sum2 = 0.f, ssq2 = 0.f;
  const int base = blockIdx.x * 32 + w * 8;
  #pragma unroll 1
  for (int it = 0; it < 8; ++it){
    const int i = base + it;
    const float slo = S[i * 128 + clo];
    const float shi = S[i * 128 + chi];
    int kk = (lane < MN) ? idx[i * MN + lane] : 0;
    fp nb = nbr + (size_t)i * (MN * NBRF);
    int k0 = __builtin_amdgcn_readlane(kk, 0);
    float tlo = T[k0 * 128 + clo];
    float thi = T[k0 * 128 + chi];
    float ev  = (lane < NBRF) ? nb[lane] : 0.f;
    float acc = 0.f;
    #pragma unroll 1
    for (int j = 0; j < MN; j++){
      float tlo_n = 0.f, thi_n = 0.f, ev_n = 0.f;
      if (j + 1 < MN){
        int kn = __builtin_amdgcn_readlane(kk, j + 1);
        tlo_n = T[kn * 128 + clo];
        thi_n = T[kn * 128 + chi];
        ev_n  = (lane < NBRF) ? nb[(j + 1) * NBRF + lane] : 0.f;
      }
      float glo = slo + tlo, ghi = shi + thi;
#define EF(q) { float s_ = rlf(ev, q); glo = fmaf(s_, wlo##q, glo); ghi = fmaf(s_, whi##q, ghi); }
      REP41(EF)
#undef EF
      float filt = fsig(fmaf(glo, sc_lo, sh_lo));
      float core = ftanh(fmaf(ghi, sc_hi, sh_hi));
      acc = fmaf(filt, core, acc);
      tlo = tlo_n; thi = thi_n; ev = ev_n;
    }
    ns[i * FD + lane] = acc;
    sum2 += acc; ssq2 = fmaf(acc, acc, ssq2);
  }
  __shared__ float red[4 * 128];
  red[w * 128 + 2 * lane    ] = sum2;
  red[w * 128 + 2 * lane + 1] = ssq2;
  __syncthreads();
  const int t = threadIdx.x;
  if (t < 128){
    const int ch = t & 63, which = t >> 6;
    float v = 0.f;
    #pragma unroll
    for (int ww = 0; ww < 4; ++ww) v += red[ww * 128 + 2 * ch + which];
    p2[blockIdx.x * 128 + t] = v;
  }
}

// ---------------- grid reduce of partials (coalesced rows -> atomics, 64-way) ----------------
__global__ void reduce_rows_kernel(const float* __restrict__ p, float* __restrict__ accum,
                                   int nrows, int ncols)
{
  const int t = threadIdx.x;   // blockDim.x == ncols
  float a = 0.f;
  for (int r = blockIdx.x; r < nrows; r += gridDim.x) a += p[r * ncols + t];
  atomicAdd(&accum[t], a);
}

__global__ void finalize1_kernel(const float* __restrict__ acc, fp g, fp b,
                                 float* __restrict__ ss1)
{
  const int c = threadIdx.x;   // 128
  const float inv = 1.f / 1200000.f;
  float mean = acc[c] * inv;
  float var  = fmaxf(acc[128 + c] * inv - mean * mean, 0.f);
  float sc   = g[c] * rsqrtf(var + EPSF);
  ss1[c] = sc;
  ss1[128 + c] = b[c] - mean * sc;
}

__global__ void finalize2_kernel(const float* __restrict__ acc, fp g, fp b,
                                 float* __restrict__ ss2)
{
  const int c = threadIdx.x;   // 64
  const float inv = 1.f / 100000.f;
  float mean = acc[c] * inv;
  float var  = fmaxf(acc[64 + c] * inv - mean * mean, 0.f);
  float sc   = g[c] * rsqrtf(var + EPSF);
  ss2[c] = sc;
  ss2[64 + c] = b[c] - mean * sc;
}

// ---------------- BN2 affine + residual tanh; optional f32 x output copy ----------------
__global__ __launch_bounds__(256) void bn2res_kernel(
    float* __restrict__ x, const float* __restrict__ ns,
    const float* __restrict__ ss2, float* __restrict__ xout)
{
  const int e = (blockIdx.x * 256 + threadIdx.x) * 4;   // grid sized exactly
  const int c = e & 63;
  float4 xv = *(const float4*)(x + e);
  float4 nv = *(const float4*)(ns + e);
  float r0 = ftanh(fmaf(nv.x, ss2[c + 0], ss2[64 + c + 0]) + xv.x);
  float r1 = ftanh(fmaf(nv.y, ss2[c + 1], ss2[64 + c + 1]) + xv.y);
  float r2 = ftanh(fmaf(nv.z, ss2[c + 2], ss2[64 + c + 2]) + xv.z);
  float r3 = ftanh(fmaf(nv.w, ss2[c + 3], ss2[64 + c + 3]) + xv.w);
  *(float4*)(x + e) = make_float4(r0, r1, r2, r3);
  if (xout){
    *(float4*)(xout + e) = make_float4(r0, r1, r2, r3);
  }
}

// ---------------- pooling: per-crystal sum of x + counts (sorted ids, run-accumulate) ----------------
__global__ __launch_bounds__(256) void pool1_kernel(
    const float* __restrict__ x, const int* __restrict__ cid,
    float* __restrict__ csum, float* __restrict__ ccnt)
{
  const int lane = threadIdx.x & 63, w = threadIdx.x >> 6;
  const int wg = blockIdx.x * 4 + w;
  const int i0 = wg * 64;
  if (i0 >= NA) return;
  const int i1 = min(i0 + 64, NA);
  int cur = -1; float acc = 0.f; int run = 0;
  for (int i = i0; i < i1; ++i){
    int cd = cid[i];
    if (cd != cur){
      if (cur >= 0){
        atomicAdd(&csum[cur * FD + lane], acc);
        if (lane == 0) atomicAdd(&ccnt[cur], (float)run);
      }
      cur = cd; acc = 0.f; run = 0;
    }
    acc += x[i * FD + lane];
    run++;
  }
  if (cur >= 0){
    atomicAdd(&csum[cur * FD + lane], acc);
    if (lane == 0) atomicAdd(&ccnt[cur], (float)run);
  }
}

// ---------------- c3 = tanh(crys_mean @ W3 + b3) per crystal ----------------
__global__ void cm3_kernel(const float* __restrict__ csum, const float* __restrict__ ccnt,
                           fp W3, fp b3, float* __restrict__ c3)
{
  const int b = blockIdx.x, t = threadIdx.x;   // 64 threads
  __shared__ float mean[64];
  float inv = 1.f / fmaxf(ccnt[b], 1.f);
  mean[t] = csum[b * FD + t] * inv;
  __syncthreads();
  float acc = b3[t];
  #pragma unroll
  for (int k = 0; k < 64; k++) acc = fmaf(mean[k], W3[k * FD + t], acc);
  c3[b * FD + t] = ftanh(acc);
}

// ---------------- a = sigmoid(<x_i, c3[cid]>); seg-sum of a*x ----------------
__global__ __launch_bounds__(256) void pool2_kernel(
    const float* __restrict__ x, const int* __restrict__ cid,
    const float* __restrict__ c3, float* __restrict__ cfs)
{
  const int lane = threadIdx.x & 63, w = threadIdx.x >> 6;
  const int wg = blockIdx.x * 4 + w;
  const int i0 = wg * 64;
  if (i0 >= NA) return;
  const int i1 = min(i0 + 64, NA);
  int cur = -1; float acc = 0.f;
  for (int i = i0; i < i1; ++i){
    int cd = cid[i];
    if (cd != cur){
      if (cur >= 0) atomicAdd(&cfs[cur * FD + lane], acc);
      cur = cd; acc = 0.f;
    }
    float xv = x[i * FD + lane];
    float p = xv * c3[cd * FD + lane];
    #pragma unroll
    for (int off = 32; off; off >>= 1) p += __shfl_xor(p, off);
    acc = fmaf(fsig(p), xv, acc);
  }
  if (cur >= 0) atomicAdd(&cfs[cur * FD + lane], acc);
}

// ---------------- head: softplus(mean @ fc + b) @ out_W + out_b ----------------
__global__ void head_kernel(const float* __restrict__ cfs, const float* __restrict__ ccnt,
                            fp fcW, fp fcb, fp oW, fp ob,
                            float* __restrict__ outp)
{
  const int b = blockIdx.x, t = threadIdx.x;   // 128 threads
  __shared__ float row[64];
  __shared__ float red[128];
  float inv = 1.f / fmaxf(ccnt[b], 1.f);
  if (t < 64) row[t] = cfs[b * FD + t] * inv;
  __syncthreads();
  float acc = fcb[t];
  #pragma unroll
  for (int k = 0; k < 64; k++) acc = fmaf(row[k], fcW[k * 128 + t], acc);
  float sp = (acc > 20.f) ? acc : log1pf(__expf(acc));
  red[t] = sp * oW[t];
  __syncthreads();
  for (int off = 64; off; off >>= 1){
    if (t < off) red[t] += red[t + off];
    __syncthreads();
  }
  if (t == 0) outp[b] = red[0] + ob[0];
}

// ---------------- workspace layout (floats) ----------------
static const size_t O_X    = 0;            // 6,400,000   x[N][64]
static const size_t O_S    = 6400000;      // 12,800,000  S[N][128]
static const size_t O_T    = 19200000;     // 12,800,000  T[N][128]
static const size_t O_NS   = 32000000;     // 6,400,000   nbr_sumed[N][64]
static const size_t O_P1   = 38400000;     // 800,000     [NBLK][256]
static const size_t O_P2   = 39200000;     // 400,000     [NBLK][128]
static const size_t O_SS1  = 39600000;     // 256
static const size_t O_SS2  = 39600256;     // 128
static const size_t O_G1   = 39600384;     // 256
static const size_t O_G2   = 39600640;     // 128
static const size_t O_CSUM = 39600768;     // 128,000
static const size_t O_CCNT = 39728768;     // 2,000
static const size_t O_C3   = 39730768;     // 128,000
static const size_t O_CFS  = 39858768;     // 128,000
static const size_t O_END  = 39986768;     // ~160 MB (fallback minimum)
static const size_t O_GATED= 39986768;     // 153,600,000  gated[1.2M][128]
static const size_t O_END2 = 193586768;    // ~774 MB (big path)

extern "C" void kernel_launch(void* const* d_in, const int* in_sizes, int n_in,
                              void* d_out, int out_size, void* d_ws, size_t ws_size,
                              hipStream_t stream)
{
  (void)in_sizes; (void)n_in; (void)out_size;
  if (ws_size < O_END * sizeof(float)) return;   // visible failure, no corruption
  const bool big = ws_size >= O_END2 * sizeof(float);

  fp atom_fea = (fp)d_in[0];
  fp nbr_fea  = (fp)d_in[1];
  const int* nbr_idx = (const int*)d_in[2];
  const int* cids    = (const int*)d_in[3];
  fp embW = (fp)d_in[4];
  fp embb = (fp)d_in[5];
  fp convW = (fp)d_in[6];
  fp convb = (fp)d_in[7];
  fp bn1g = (fp)d_in[8];
  fp bn1b = (fp)d_in[9];
  fp bn2g = (fp)d_in[10];
  fp bn2b = (fp)d_in[11];
  fp W3W  = (fp)d_in[12];
  fp W3b  = (fp)d_in[13];
  fp fcW  = (fp)d_in[14];
  fp fcb  = (fp)d_in[15];
  fp oW   = (fp)d_in[16];
  fp ob   = (fp)d_in[17];

  float* out_head = (float*)d_out;
  float* out_x    = out_head + NC;

  float* W  = (float*)d_ws;
  float* x    = W + O_X;
  float* S    = W + O_S;
  float* T    = W + O_T;
  float* ns   = W + O_NS;
  float* p1   = W + O_P1;
  float* p2   = W + O_P2;
  float* ss1  = W + O_SS1;
  float* ss2  = W + O_SS2;
  float* g1s  = W + O_G1;
  float* g2s  = W + O_G2;
  float* csum = W + O_CSUM;
  float* ccnt = W + O_CCNT;
  float* c3   = W + O_C3;
  float* cfs  = W + O_CFS;
  float* gated= W + O_GATED;

  // zero crystal accumulators (csum..cfs contiguous, 386,000 floats)
  zero_kernel<<<128, 256, 0, stream>>>(csum, 386000);

  emb_kernel<<<NBLK, 256, 0, stream>>>(atom_fea, embW, embb, x);

  for (int l = 0; l < 3; ++l){
    fp Wl = convW + (size_t)l * 169 * 128;
    stw_kernel<<<NBLK, 256, 0, stream>>>(x, Wl,            convb + l * 128, S);  // self rows 0..63
    stw_kernel<<<NBLK, 256, 0, stream>>>(x, Wl + 64 * 128, (fp)nullptr,     T);  // nbr rows 64..127
    zero_kernel<<<1, 256, 0, stream>>>(g1s, 384);  // g1s(256)+g2s(128) contiguous
    if (big){
      edge_stats_store_kernel<<<NBLK, 256, 0, stream>>>(S, T, nbr_fea, nbr_idx, Wl + 128 * 128, p1, gated);
      reduce_rows_kernel<<<64, 256, 0, stream>>>(p1, g1s, NBLK, 256);
      finalize1_kernel<<<1, 128, 0, stream>>>(g1s, bn1g + l * 128, bn1b + l * 128, ss1);
      edge_apply_load_kernel<<<NBLK, 256, 0, stream>>>(gated, ss1, ns, p2);
    } else {
      edge_stats_kernel<<<NBLK, 256, 0, stream>>>(S, T, nbr_fea, nbr_idx, Wl + 128 * 128, p1);
      reduce_rows_kernel<<<64, 256, 0, stream>>>(p1, g1s, NBLK, 256);
      finalize1_kernel<<<1, 128, 0, stream>>>(g1s, bn1g + l * 128, bn1b + l * 128, ss1);
      edge_apply_kernel<<<NBLK, 256, 0, stream>>>(S, T, nbr_fea, nbr_idx, Wl + 128 * 128, ss1, ns, p2);
    }
    reduce_rows_kernel<<<64, 128, 0, stream>>>(p2, g2s, NBLK, 128);
    finalize2_kernel<<<1, 64, 0, stream>>>(g2s, bn2g + l * 64, bn2b + l * 64, ss2);
    bn2res_kernel<<<6250, 256, 0, stream>>>(x, ns, ss2, (l == 2) ? out_x : (float*)nullptr);
  }

  pool1_kernel<<<391, 256, 0, stream>>>(x, cids, csum, ccnt);
  cm3_kernel<<<NC, 64, 0, stream>>>(csum, ccnt, W3W, W3b, c3);
  pool2_kernel<<<391, 256, 0, stream>>>(x, cids, c3, cfs);
  head_kernel<<<NC, 128, 0, stream>>>(cfs, ccnt, fcW, fcb, oW, ob, out_head);
}

// Round 5
// 2442.323 us; speedup vs baseline: 1.1745x; 1.1745x over previous
//
#include <hip/hip_runtime.h>
#include <hip/hip_bf16.h>

// CrystalGraphConvNet forward, MI355X. All tensors FLOAT32.
// d_out = [out(2000), x(6.4M)] float32.
//
// Decomposition: gated = S[i] + T[nbr_idx[i,j]] + e_ij @ W_edge, with
// S = x@W[0:64]+b, T = x@W[64:128] precomputed per atom per layer.
// BN over batch => stats pass (stores gated, 614MB) + streaming apply pass.
//
// R9 change: revert R8 wave-split (regressed 429->542: duplicated readlanes,
// VALU busy 210->406us; VGPR=32 proves pins can't stop AGPR allocation).
// New stats kernel = R7 one-wave-both-halves structure with:
//  (a) e-broadcast from LDS (stage 12x41 block/atom; uniform-address ds_read
//      = free broadcast on LDS pipe) -- removes 41 readlanes/edge from VALU;
//  (b) j-unroll x4 -- 4 edges share each weight-register access, amortizing
//      any per-use AGPR-read tax 82 -> ~20/edge.
// Accumulation & fma order bit-identical to R7. Apply pass unchanged (planar).

#define NA    100000
#define MN    12
#define NC    2000
#define ORIGF 92
#define NBRF  41
#define FD    64
#define NBLK  3125     // edge-kernel blocks: 3125 * 32 atoms = 100000 exactly
#define EPSF  1e-5f

#define REP28(X) X(0)X(1)X(2)X(3)X(4)X(5)X(6)X(7)X(8)X(9)X(10)X(11)X(12)X(13)X(14)X(15)X(16)X(17)X(18)X(19)X(20)X(21)X(22)X(23)X(24)X(25)X(26)X(27)
#define REP41(X) X(0)X(1)X(2)X(3)X(4)X(5)X(6)X(7)X(8)X(9)X(10)X(11)X(12)X(13)X(14)X(15)X(16)X(17)X(18)X(19)X(20)X(21)X(22)X(23)X(24)X(25)X(26)X(27)X(28)X(29)X(30)X(31)X(32)X(33)X(34)X(35)X(36)X(37)X(38)X(39)X(40)
#define REP64(X) X(0)X(1)X(2)X(3)X(4)X(5)X(6)X(7)X(8)X(9)X(10)X(11)X(12)X(13)X(14)X(15)X(16)X(17)X(18)X(19)X(20)X(21)X(22)X(23)X(24)X(25)X(26)X(27)X(28)X(29)X(30)X(31)X(32)X(33)X(34)X(35)X(36)X(37)X(38)X(39)X(40)X(41)X(42)X(43)X(44)X(45)X(46)X(47)X(48)X(49)X(50)X(51)X(52)X(53)X(54)X(55)X(56)X(57)X(58)X(59)X(60)X(61)X(62)X(63)

typedef const float* fp;

__device__ __forceinline__ float rlf(float v, int q){
  return __int_as_float(__builtin_amdgcn_readlane(__float_as_int(v), q));
}
__device__ __forceinline__ float fsig(float z){
  z = fminf(fmaxf(z, -30.f), 30.f);
  return 1.f / (1.f + __expf(-z));
}
__device__ __forceinline__ float ftanh(float z){
  z = fminf(fmaxf(z, -15.f), 15.f);
  float e = __expf(2.f * z);
  return (e - 1.f) / (e + 1.f);
}

// ---------------- zero scratch ----------------
__global__ void zero_kernel(float* __restrict__ p, int n){
  for (int i = blockIdx.x * blockDim.x + threadIdx.x; i < n; i += gridDim.x * blockDim.x)
    p[i] = 0.f;
}

// ---------------- embedding: x = atom_fea @ emb_W + emb_b ----------------
__global__ __launch_bounds__(256, 2) void emb_kernel(
    fp __restrict__ af, fp __restrict__ W, fp __restrict__ b,
    float* __restrict__ x)
{
  const int lane = threadIdx.x & 63, w = threadIdx.x >> 6;
#define EA(k) float wa##k = W[k * FD + lane];
  REP64(EA)
#undef EA
#define EB(k) float wb##k = W[(k + 64) * FD + lane];
  REP28(EB)
#undef EB
  const float bias = b[lane];
  const int base = blockIdx.x * 32 + w * 8;
  #pragma unroll 1
  for (int it = 0; it < 8; ++it){
    const int i = base + it;
    float ev0 = af[i * ORIGF + lane];
    float ev1 = (lane < 28) ? af[i * ORIGF + 64 + lane] : 0.f;
    float acc = bias;
#define FA(k) acc = fmaf(rlf(ev0, k), wa##k, acc);
    REP64(FA)
#undef FA
#define FB(k) acc = fmaf(rlf(ev1, k), wb##k, acc);
    REP28(FB)
#undef FB
    x[i * FD + lane] = acc;
  }
}

// ---------------- stw: out[N][128] = xin[N][64] @ W[64][128] (+bias) ----------------
__global__ __launch_bounds__(256, 4) void stw_kernel(
    const float* __restrict__ xin, fp __restrict__ W, fp __restrict__ bias,
    float* __restrict__ out)
{
  const int lane = threadIdx.x & 63, w = threadIdx.x >> 6;
  const int ch = (w & 1) * 64 + lane;
#define SW(k) float wv##k = W[k * 128 + ch];
  REP64(SW)
#undef SW
  const float bb = bias ? bias[ch] : 0.f;
  const int base = blockIdx.x * 32 + (w >> 1) * 16;
  #pragma unroll 1
  for (int it = 0; it < 16; ++it){
    const int i = base + it;
    float xv = xin[i * FD + lane];
    float acc = bb;
#define SF(k) acc = fmaf(rlf(xv, k), wv##k, acc);
    REP64(SF)
#undef SF
    out[i * 128 + ch] = acc;
  }
}

// ---------------- edge stats (fallback: no store) ----------------
__global__ __launch_bounds__(256, 2) void edge_stats_kernel(
    const float* __restrict__ S, const float* __restrict__ T,
    fp __restrict__ nbr, const int* __restrict__ idx,
    fp __restrict__ We, float* __restrict__ p1)   // p1: [NBLK][256] coalesced
{
  const int lane = threadIdx.x & 63, w = threadIdx.x >> 6;
  const int clo = lane, chi = lane + 64;
#define DW(q) float wlo##q = We[q * 128 + clo], whi##q = We[q * 128 + chi];
  REP41(DW)
#undef DW
  float sum_lo = 0.f, ssq_lo = 0.f, sum_hi = 0.f, ssq_hi = 0.f;
  const int base = blockIdx.x * 32 + w * 8;
  #pragma unroll 1
  for (int it = 0; it < 8; ++it){
    const int i = base + it;
    const float slo = S[i * 128 + clo];
    const float shi = S[i * 128 + chi];
    int kk = (lane < MN) ? idx[i * MN + lane] : 0;
    fp nb = nbr + (size_t)i * (MN * NBRF);
    int k0 = __builtin_amdgcn_readlane(kk, 0);
    float tlo = T[k0 * 128 + clo];
    float thi = T[k0 * 128 + chi];
    float ev  = (lane < NBRF) ? nb[lane] : 0.f;
    #pragma unroll 1
    for (int j = 0; j < MN; j++){
      float tlo_n = 0.f, thi_n = 0.f, ev_n = 0.f;
      if (j + 1 < MN){
        int kn = __builtin_amdgcn_readlane(kk, j + 1);
        tlo_n = T[kn * 128 + clo];
        thi_n = T[kn * 128 + chi];
        ev_n  = (lane < NBRF) ? nb[(j + 1) * NBRF + lane] : 0.f;
      }
      float glo = slo + tlo, ghi = shi + thi;
#define EF(q) { float s_ = rlf(ev, q); glo = fmaf(s_, wlo##q, glo); ghi = fmaf(s_, whi##q, ghi); }
      REP41(EF)
#undef EF
      sum_lo += glo; ssq_lo = fmaf(glo, glo, ssq_lo);
      sum_hi += ghi; ssq_hi = fmaf(ghi, ghi, ssq_hi);
      tlo = tlo_n; thi = thi_n; ev = ev_n;
    }
  }
  __shared__ float red[4 * 512];
  red[w * 512 + 2 * clo    ] = sum_lo;
  red[w * 512 + 2 * clo + 1] = ssq_lo;
  red[w * 512 + 2 * chi    ] = sum_hi;
  red[w * 512 + 2 * chi + 1] = ssq_hi;
  __syncthreads();
  const int t = threadIdx.x;            // stat id: (t>>7)*128 channels = sum|ssq
  const int ch = t & 127, which = t >> 7;
  float v = 0.f;
  #pragma unroll
  for (int ww = 0; ww < 4; ++ww) v += red[ww * 512 + 2 * ch + which];
  p1[blockIdx.x * 256 + t] = v;
}

// ---------------- edge stats + gated store (big-ws path, R9) ----------------
// One wave = both channel halves of 8 atoms (R7 structure). e-features staged
// in LDS per atom; per-(edge,q) broadcast via uniform-address ds_read (free,
// LDS pipe) instead of v_readlane (VALU). j unrolled x4 so 4 edges share each
// weight-register access. gated layout PLANAR [edge][128].
__global__ __launch_bounds__(256, 2) void edge_stats_store_kernel(
    const float* __restrict__ S, const float* __restrict__ T,
    fp __restrict__ nbr, const int* __restrict__ idx,
    fp __restrict__ We, float* __restrict__ p1, float* __restrict__ gated)
{
  const int lane = threadIdx.x & 63, w = threadIdx.x >> 6;
  const int clo = lane, chi = lane + 64;
#define DW(q) float wlo##q = We[q * 128 + clo], whi##q = We[q * 128 + chi];
  REP41(DW)
#undef DW
  __shared__ float elds[4][MN * NBRF];    // 4 x 492 floats
  float sum_lo = 0.f, ssq_lo = 0.f, sum_hi = 0.f, ssq_hi = 0.f;
  const int base = blockIdx.x * 32 + w * 8;
  #pragma unroll 1
  for (int it = 0; it < 8; ++it){
    const int i = base + it;
    const float slo = S[i * 128 + clo];
    const float shi = S[i * 128 + chi];
    int kk = (lane < MN) ? idx[i * MN + lane] : 0;
    fp nb = nbr + (size_t)i * (MN * NBRF);
    // stage this atom's 12x41 edge features into LDS (coalesced)
    #pragma unroll
    for (int r = 0; r < 7; ++r) elds[w][r * 64 + lane] = nb[r * 64 + lane];
    if (lane < MN * NBRF - 448) elds[w][448 + lane] = nb[448 + lane];
    asm volatile("s_waitcnt lgkmcnt(0)" ::: "memory");   // same-wave LDS visibility
    #pragma unroll 1
    for (int jg = 0; jg < MN / 4; ++jg){
      const int j0 = jg * 4;
      int k0 = __builtin_amdgcn_readlane(kk, j0);
      int k1 = __builtin_amdgcn_readlane(kk, j0 + 1);
      int k2 = __builtin_amdgcn_readlane(kk, j0 + 2);
      int k3 = __builtin_amdgcn_readlane(kk, j0 + 3);
      float g0lo = slo + T[k0 * 128 + clo], g0hi = shi + T[k0 * 128 + chi];
      float g1lo = slo + T[k1 * 128 + clo], g1hi = shi + T[k1 * 128 + chi];
      float g2lo = slo + T[k2 * 128 + clo], g2hi = shi + T[k2 * 128 + chi];
      float g3lo = slo + T[k3 * 128 + clo], g3hi = shi + T[k3 * 128 + chi];
      const float* eb = &elds[w][j0 * NBRF];
#define EF(q) { float e0_ = eb[q]; float e1_ = eb[NBRF + q]; \
                float e2_ = eb[2 * NBRF + q]; float e3_ = eb[3 * NBRF + q]; \
                g0lo = fmaf(e0_, wlo##q, g0lo); g0hi = fmaf(e0_, whi##q, g0hi); \
                g1lo = fmaf(e1_, wlo##q, g1lo); g1hi = fmaf(e1_, whi##q, g1hi); \
                g2lo = fmaf(e2_, wlo##q, g2lo); g2hi = fmaf(e2_, whi##q, g2hi); \
                g3lo = fmaf(e3_, wlo##q, g3lo); g3hi = fmaf(e3_, whi##q, g3hi); }
      REP41(EF)
#undef EF
      float* gb = gated + (((size_t)(i * MN + j0)) << 7);
      gb[lane]       = g0lo; gb[64 + lane]  = g0hi;
      gb[128 + lane] = g1lo; gb[192 + lane] = g1hi;
      gb[256 + lane] = g2lo; gb[320 + lane] = g2hi;
      gb[384 + lane] = g3lo; gb[448 + lane] = g3hi;
      // stats in j order (bit-identical to sequential accumulation)
      sum_lo += g0lo; ssq_lo = fmaf(g0lo, g0lo, ssq_lo);
      sum_hi += g0hi; ssq_hi = fmaf(g0hi, g0hi, ssq_hi);
      sum_lo += g1lo; ssq_lo = fmaf(g1lo, g1lo, ssq_lo);
      sum_hi += g1hi; ssq_hi = fmaf(g1hi, g1hi, ssq_hi);
      sum_lo += g2lo; ssq_lo = fmaf(g2lo, g2lo, ssq_lo);
      sum_hi += g2hi; ssq_hi = fmaf(g2hi, g2hi, ssq_hi);
      sum_lo += g3lo; ssq_lo = fmaf(g3lo, g3lo, ssq_lo);
      sum_hi += g3hi; ssq_hi = fmaf(g3hi, g3hi, ssq_hi);
    }
  }
  __shared__ float red[4 * 512];
  red[w * 512 + 2 * clo    ] = sum_lo;
  red[w * 512 + 2 * clo + 1] = ssq_lo;
  red[w * 512 + 2 * chi    ] = sum_hi;
  red[w * 512 + 2 * chi + 1] = ssq_hi;
  __syncthreads();
  const int t = threadIdx.x;            // stat id: (t>>7)*128 channels = sum|ssq
  const int ch = t & 127, which = t >> 7;
  float v = 0.f;
  #pragma unroll
  for (int ww = 0; ww < 4; ++ww) v += red[ww * 512 + 2 * ch + which];
  p1[blockIdx.x * 256 + t] = v;
}

// ---------------- edge apply from stored gated (big-ws path) ----------------
// Pure stream: planar gated [edge][128]; BN1 affine, sig*tanh, sum_j.
__global__ __launch_bounds__(256, 4) void edge_apply_load_kernel(
    const float* __restrict__ gated, const float* __restrict__ ss1,
    float* __restrict__ ns, float* __restrict__ p2)   // p2: [NBLK][128]
{
  const int lane = threadIdx.x & 63, w = threadIdx.x >> 6;
  const float sc_lo = ss1[lane],      sh_lo = ss1[128 + lane];
  const float sc_hi = ss1[64 + lane], sh_hi = ss1[192 + lane];
  float sum2 = 0.f, ssq2 = 0.f;
  const int base = blockIdx.x * 32 + w * 8;
  #pragma unroll 1
  for (int it = 0; it < 8; ++it){
    const int i = base + it;
    fp gb = gated + (((size_t)i * MN) << 7);
    float acc = 0.f;
    #pragma unroll
    for (int j = 0; j < MN; ++j){
      float glo = gb[(j << 7) + lane];
      float ghi = gb[(j << 7) + 64 + lane];
      float filt = fsig(fmaf(glo, sc_lo, sh_lo));
      float core = ftanh(fmaf(ghi, sc_hi, sh_hi));
      acc = fmaf(filt, core, acc);
    }
    ns[i * FD + lane] = acc;
    sum2 += acc; ssq2 = fmaf(acc, acc, ssq2);
  }
  __shared__ float red[4 * 128];
  red[w * 128 + 2 * lane    ] = sum2;
  red[w * 128 + 2 * lane + 1] = ssq2;
  __syncthreads();
  const int t = threadIdx.x;
  if (t < 128){
    const int ch = t & 63, which = t >> 6;
    float v = 0.f;
    #pragma unroll
    for (int ww = 0; ww < 4; ++ww) v += red[ww * 128 + 2 * ch + which];
    p2[blockIdx.x * 128 + t] = v;
  }
}

// ---------------- edge apply (fallback: recompute) ----------------
__global__ __launch_bounds__(256, 2) void edge_apply_kernel(
    const float* __restrict__ S, const float* __restrict__ T,
    fp __restrict__ nbr, const int* __restrict__ idx,
    fp __restrict__ We, const float* __restrict__ ss1,
    float* __restrict__ ns, float* __restrict__ p2)   // p2: [NBLK][128]
{
  const int lane = threadIdx.x & 63, w = threadIdx.x >> 6;
  const int clo = lane, chi = lane + 64;
#define DW(q) float wlo##q = We[q * 128 + clo], whi##q = We[q * 128 + chi];
  REP41(DW)
#undef DW
  const float sc_lo = ss1[clo],       sh_lo = ss1[128 + clo];
  const float sc_hi = ss1[chi],       sh_hi = ss1[128 + chi];
  float sum2 = 0.f, ssq2 = 0.f;
  const int base = blockIdx.x * 32 + w * 8;
  #pragma unroll 1
  for (int it = 0; it < 8; ++it){
    const int i = base + it;
    const float slo = S[i * 128 + clo];
    const float shi = S[i * 128 + chi];
    int kk = (lane < MN) ? idx[i * MN + lane] : 0;
    fp nb = nbr + (size_t)i * (MN * NBRF);
    int k0 = __builtin_amdgcn_readlane(kk, 0);
    float tlo = T[k0 * 128 + clo];
    float thi = T[k0 * 128 + chi];
    float ev  = (lane < NBRF) ? nb[lane] : 0.f;
    float acc = 0.f;
    #pragma unroll 1
    for (int j = 0; j < MN; j++){
      float tlo_n = 0.f, thi_n = 0.f, ev_n = 0.f;
      if (j + 1 < MN){
        int kn = __builtin_amdgcn_readlane(kk, j + 1);
        tlo_n = T[kn * 128 + clo];
        thi_n = T[kn * 128 + chi];
        ev_n  = (lane < NBRF) ? nb[(j + 1) * NBRF + lane] : 0.f;
      }
      float glo = slo + tlo, ghi = shi + thi;
#define EF(q) { float s_ = rlf(ev, q); glo = fmaf(s_, wlo##q, glo); ghi = fmaf(s_, whi##q, ghi); }
      REP41(EF)
#undef EF
      float filt = fsig(fmaf(glo, sc_lo, sh_lo));
      float core = ftanh(fmaf(ghi, sc_hi, sh_hi));
      acc = fmaf(filt, core, acc);
      tlo = tlo_n; thi = thi_n; ev = ev_n;
    }
    ns[i * FD + lane] = acc;
    sum2 += acc; ssq2 = fmaf(acc, acc, ssq2);
  }
  __shared__ float red[4 * 128];
  red[w * 128 + 2 * lane    ] = sum2;
  red[w * 128 + 2 * lane + 1] = ssq2;
  __syncthreads();
  const int t = threadIdx.x;
  if (t < 128){
    const int ch = t & 63, which = t >> 6;
    float v = 0.f;
    #pragma unroll
    for (int ww = 0; ww < 4; ++ww) v += red[ww * 128 + 2 * ch + which];
    p2[blockIdx.x * 128 + t] = v;
  }
}

// ---------------- grid reduce of partials (coalesced rows -> atomics, 64-way) ----------------
__global__ void reduce_rows_kernel(const float* __restrict__ p, float* __restrict__ accum,
                                   int nrows, int ncols)
{
  const int t = threadIdx.x;   // blockDim.x == ncols
  float a = 0.f;
  for (int r = blockIdx.x; r < nrows; r += gridDim.x) a += p[r * ncols + t];
  atomicAdd(&accum[t], a);
}

__global__ void finalize1_kernel(const float* __restrict__ acc, fp g, fp b,
                                 float* __restrict__ ss1)
{
  const int c = threadIdx.x;   // 128
  const float inv = 1.f / 1200000.f;
  float mean = acc[c] * inv;
  float var  = fmaxf(acc[128 + c] * inv - mean * mean, 0.f);
  float sc   = g[c] * rsqrtf(var + EPSF);
  ss1[c] = sc;
  ss1[128 + c] = b[c] - mean * sc;
}

__global__ void finalize2_kernel(const float* __restrict__ acc, fp g, fp b,
                                 float* __restrict__ ss2)
{
  const int c = threadIdx.x;   // 64
  const float inv = 1.f / 100000.f;
  float mean = acc[c] * inv;
  float var  = fmaxf(acc[64 + c] * inv - mean * mean, 0.f);
  float sc   = g[c] * rsqrtf(var + EPSF);
  ss2[c] = sc;
  ss2[64 + c] = b[c] - mean * sc;
}

// ---------------- BN2 affine + residual tanh; optional f32 x output copy ----------------
__global__ __launch_bounds__(256) void bn2res_kernel(
    float* __restrict__ x, const float* __restrict__ ns,
    const float* __restrict__ ss2, float* __restrict__ xout)
{
  const int e = (blockIdx.x * 256 + threadIdx.x) * 4;   // grid sized exactly
  const int c = e & 63;
  float4 xv = *(const float4*)(x + e);
  float4 nv = *(const float4*)(ns + e);
  float r0 = ftanh(fmaf(nv.x, ss2[c + 0], ss2[64 + c + 0]) + xv.x);
  float r1 = ftanh(fmaf(nv.y, ss2[c + 1], ss2[64 + c + 1]) + xv.y);
  float r2 = ftanh(fmaf(nv.z, ss2[c + 2], ss2[64 + c + 2]) + xv.z);
  float r3 = ftanh(fmaf(nv.w, ss2[c + 3], ss2[64 + c + 3]) + xv.w);
  *(float4*)(x + e) = make_float4(r0, r1, r2, r3);
  if (xout){
    *(float4*)(xout + e) = make_float4(r0, r1, r2, r3);
  }
}

// ---------------- pooling: per-crystal sum of x + counts (sorted ids, run-accumulate) ----------------
__global__ __launch_bounds__(256) void pool1_kernel(
    const float* __restrict__ x, const int* __restrict__ cid,
    float* __restrict__ csum, float* __restrict__ ccnt)
{
  const int lane = threadIdx.x & 63, w = threadIdx.x >> 6;
  const int wg = blockIdx.x * 4 + w;
  const int i0 = wg * 64;
  if (i0 >= NA) return;
  const int i1 = min(i0 + 64, NA);
  int cur = -1; float acc = 0.f; int run = 0;
  for (int i = i0; i < i1; ++i){
    int cd = cid[i];
    if (cd != cur){
      if (cur >= 0){
        atomicAdd(&csum[cur * FD + lane], acc);
        if (lane == 0) atomicAdd(&ccnt[cur], (float)run);
      }
      cur = cd; acc = 0.f; run = 0;
    }
    acc += x[i * FD + lane];
    run++;
  }
  if (cur >= 0){
    atomicAdd(&csum[cur * FD + lane], acc);
    if (lane == 0) atomicAdd(&ccnt[cur], (float)run);
  }
}

// ---------------- c3 = tanh(crys_mean @ W3 + b3) per crystal ----------------
__global__ void cm3_kernel(const float* __restrict__ csum, const float* __restrict__ ccnt,
                           fp W3, fp b3, float* __restrict__ c3)
{
  const int b = blockIdx.x, t = threadIdx.x;   // 64 threads
  __shared__ float mean[64];
  float inv = 1.f / fmaxf(ccnt[b], 1.f);
  mean[t] = csum[b * FD + t] * inv;
  __syncthreads();
  float acc = b3[t];
  #pragma unroll
  for (int k = 0; k < 64; k++) acc = fmaf(mean[k], W3[k * FD + t], acc);
  c3[b * FD + t] = ftanh(acc);
}

// ---------------- a = sigmoid(<x_i, c3[cid]>); seg-sum of a*x ----------------
__global__ __launch_bounds__(256) void pool2_kernel(
    const float* __restrict__ x, const int* __restrict__ cid,
    const float* __restrict__ c3, float* __restrict__ cfs)
{
  const int lane = threadIdx.x & 63, w = threadIdx.x >> 6;
  const int wg = blockIdx.x * 4 + w;
  const int i0 = wg * 64;
  if (i0 >= NA) return;
  const int i1 = min(i0 + 64, NA);
  int cur = -1; float acc = 0.f;
  for (int i = i0; i < i1; ++i){
    int cd = cid[i];
    if (cd != cur){
      if (cur >= 0) atomicAdd(&cfs[cur * FD + lane], acc);
      cur = cd; acc = 0.f;
    }
    float xv = x[i * FD + lane];
    float p = xv * c3[cd * FD + lane];
    #pragma unroll
    for (int off = 32; off; off >>= 1) p += __shfl_xor(p, off);
    acc = fmaf(fsig(p), xv, acc);
  }
  if (cur >= 0) atomicAdd(&cfs[cur * FD + lane], acc);
}

// ---------------- head: softplus(mean @ fc + b) @ out_W + out_b ----------------
__global__ void head_kernel(const float* __restrict__ cfs, const float* __restrict__ ccnt,
                            fp fcW, fp fcb, fp oW, fp ob,
                            float* __restrict__ outp)
{
  const int b = blockIdx.x, t = threadIdx.x;   // 128 threads
  __shared__ float row[64];
  __shared__ float red[128];
  float inv = 1.f / fmaxf(ccnt[b], 1.f);
  if (t < 64) row[t] = cfs[b * FD + t] * inv;
  __syncthreads();
  float acc = fcb[t];
  #pragma unroll
  for (int k = 0; k < 64; k++) acc = fmaf(row[k], fcW[k * 128 + t], acc);
  float sp = (acc > 20.f) ? acc : log1pf(__expf(acc));
  red[t] = sp * oW[t];
  __syncthreads();
  for (int off = 64; off; off >>= 1){
    if (t < off) red[t] += red[t + off];
    __syncthreads();
  }
  if (t == 0) outp[b] = red[0] + ob[0];
}

// ---------------- workspace layout (floats) ----------------
static const size_t O_X    = 0;            // 6,400,000   x[N][64]
static const size_t O_S    = 6400000;      // 12,800,000  S[N][128]
static const size_t O_T    = 19200000;     // 12,800,000  T[N][128]
static const size_t O_NS   = 32000000;     // 6,400,000   nbr_sumed[N][64]
static const size_t O_P1   = 38400000;     // 800,000     [NBLK][256]
static const size_t O_P2   = 39200000;     // 400,000     [NBLK][128]
static const size_t O_SS1  = 39600000;     // 256
static const size_t O_SS2  = 39600256;     // 128
static const size_t O_G1   = 39600384;     // 256
static const size_t O_G2   = 39600640;     // 128
static const size_t O_CSUM = 39600768;     // 128,000
static const size_t O_CCNT = 39728768;     // 2,000
static const size_t O_C3   = 39730768;     // 128,000
static const size_t O_CFS  = 39858768;     // 128,000
static const size_t O_END  = 39986768;     // ~160 MB (fallback minimum)
static const size_t O_GATED= 39986768;     // 153,600,000  gated[1.2M][128]
static const size_t O_END2 = 193586768;    // ~774 MB (big path)

extern "C" void kernel_launch(void* const* d_in, const int* in_sizes, int n_in,
                              void* d_out, int out_size, void* d_ws, size_t ws_size,
                              hipStream_t stream)
{
  (void)in_sizes; (void)n_in; (void)out_size;
  if (ws_size < O_END * sizeof(float)) return;   // visible failure, no corruption
  const bool big = ws_size >= O_END2 * sizeof(float);

  fp atom_fea = (fp)d_in[0];
  fp nbr_fea  = (fp)d_in[1];
  const int* nbr_idx = (const int*)d_in[2];
  const int* cids    = (const int*)d_in[3];
  fp embW = (fp)d_in[4];
  fp embb = (fp)d_in[5];
  fp convW = (fp)d_in[6];
  fp convb = (fp)d_in[7];
  fp bn1g = (fp)d_in[8];
  fp bn1b = (fp)d_in[9];
  fp bn2g = (fp)d_in[10];
  fp bn2b = (fp)d_in[11];
  fp W3W  = (fp)d_in[12];
  fp W3b  = (fp)d_in[13];
  fp fcW  = (fp)d_in[14];
  fp fcb  = (fp)d_in[15];
  fp oW   = (fp)d_in[16];
  fp ob   = (fp)d_in[17];

  float* out_head = (float*)d_out;
  float* out_x    = out_head + NC;

  float* W  = (float*)d_ws;
  float* x    = W + O_X;
  float* S    = W + O_S;
  float* T    = W + O_T;
  float* ns   = W + O_NS;
  float* p1   = W + O_P1;
  float* p2   = W + O_P2;
  float* ss1  = W + O_SS1;
  float* ss2  = W + O_SS2;
  float* g1s  = W + O_G1;
  float* g2s  = W + O_G2;
  float* csum = W + O_CSUM;
  float* ccnt = W + O_CCNT;
  float* c3   = W + O_C3;
  float* cfs  = W + O_CFS;
  float* gated= W + O_GATED;

  // zero crystal accumulators (csum..cfs contiguous, 386,000 floats)
  zero_kernel<<<128, 256, 0, stream>>>(csum, 386000);

  emb_kernel<<<NBLK, 256, 0, stream>>>(atom_fea, embW, embb, x);

  for (int l = 0; l < 3; ++l){
    fp Wl = convW + (size_t)l * 169 * 128;
    stw_kernel<<<NBLK, 256, 0, stream>>>(x, Wl,            convb + l * 128, S);  // self rows 0..63
    stw_kernel<<<NBLK, 256, 0, stream>>>(x, Wl + 64 * 128, (fp)nullptr,     T);  // nbr rows 64..127
    zero_kernel<<<1, 256, 0, stream>>>(g1s, 384);  // g1s(256)+g2s(128) contiguous
    if (big){
      edge_stats_store_kernel<<<NBLK, 256, 0, stream>>>(S, T, nbr_fea, nbr_idx, Wl + 128 * 128, p1, gated);
      reduce_rows_kernel<<<64, 256, 0, stream>>>(p1, g1s, NBLK, 256);
      finalize1_kernel<<<1, 128, 0, stream>>>(g1s, bn1g + l * 128, bn1b + l * 128, ss1);
      edge_apply_load_kernel<<<NBLK, 256, 0, stream>>>(gated, ss1, ns, p2);
    } else {
      edge_stats_kernel<<<NBLK, 256, 0, stream>>>(S, T, nbr_fea, nbr_idx, Wl + 128 * 128, p1);
      reduce_rows_kernel<<<64, 256, 0, stream>>>(p1, g1s, NBLK, 256);
      finalize1_kernel<<<1, 128, 0, stream>>>(g1s, bn1g + l * 128, bn1b + l * 128, ss1);
      edge_apply_kernel<<<NBLK, 256, 0, stream>>>(S, T, nbr_fea, nbr_idx, Wl + 128 * 128, ss1, ns, p2);
    }
    reduce_rows_kernel<<<64, 128, 0, stream>>>(p2, g2s, NBLK, 128);
    finalize2_kernel<<<1, 64, 0, stream>>>(g2s, bn2g + l * 64, bn2b + l * 64, ss2);
    bn2res_kernel<<<6250, 256, 0, stream>>>(x, ns, ss2, (l == 2) ? out_x : (float*)nullptr);
  }

  pool1_kernel<<<391, 256, 0, stream>>>(x, cids, csum, ccnt);
  cm3_kernel<<<NC, 64, 0, stream>>>(csum, ccnt, W3W, W3b, c3);
  pool2_kernel<<<391, 256, 0, stream>>>(x, cids, c3, cfs);
  head_kernel<<<NC, 128, 0, stream>>>(cfs, ccnt, fcW, fcb, oW, ob, out_head);
}

// Round 6
// 2375.182 us; speedup vs baseline: 1.2077x; 1.0283x over previous
//
#include <hip/hip_runtime.h>
#include <hip/hip_bf16.h>

// CrystalGraphConvNet forward, MI355X. All tensors FLOAT32.
// d_out = [out(2000), x(6.4M)] float32.
//
// Decomposition: gated = S[i] + T[nbr_idx[i,j]] + e_ij @ W_edge, with
// S = x@W[0:64]+b, T = x@W[64:128] precomputed per atom per layer.
// BN over batch => stats pass (stores gated, 614MB) + streaming apply pass.
//
// R10 change: wave-split channel halves in edge_stats_store (waves 0,2 = ch
// 0..63; waves 1,3 = ch 64..127; 16 atoms/wave), keeping R9's LDS e-broadcast
// + j-unroll x4. R9 evidence: dur 392us with VALUBusy 34% (issue 133us, as
// modeled) but occupancy 39% (VGPR=64 visible, ~165 total => AGPR spill) =>
// latency-bound on T-gathers. R8's wave-split failure was duplicated
// readlanes; R9 removed readlanes, so the split now costs nothing on VALU and
// buys ~75-reg waves => ~6 waves/SIMD. Stats reduction = R8's verified
// wave->half mapping. Per-channel fma order bit-identical to R9.

#define NA    100000
#define MN    12
#define NC    2000
#define ORIGF 92
#define NBRF  41
#define FD    64
#define NBLK  3125     // edge-kernel blocks: 3125 * 32 atoms = 100000 exactly
#define EPSF  1e-5f

#define REP28(X) X(0)X(1)X(2)X(3)X(4)X(5)X(6)X(7)X(8)X(9)X(10)X(11)X(12)X(13)X(14)X(15)X(16)X(17)X(18)X(19)X(20)X(21)X(22)X(23)X(24)X(25)X(26)X(27)
#define REP41(X) X(0)X(1)X(2)X(3)X(4)X(5)X(6)X(7)X(8)X(9)X(10)X(11)X(12)X(13)X(14)X(15)X(16)X(17)X(18)X(19)X(20)X(21)X(22)X(23)X(24)X(25)X(26)X(27)X(28)X(29)X(30)X(31)X(32)X(33)X(34)X(35)X(36)X(37)X(38)X(39)X(40)
#define REP64(X) X(0)X(1)X(2)X(3)X(4)X(5)X(6)X(7)X(8)X(9)X(10)X(11)X(12)X(13)X(14)X(15)X(16)X(17)X(18)X(19)X(20)X(21)X(22)X(23)X(24)X(25)X(26)X(27)X(28)X(29)X(30)X(31)X(32)X(33)X(34)X(35)X(36)X(37)X(38)X(39)X(40)X(41)X(42)X(43)X(44)X(45)X(46)X(47)X(48)X(49)X(50)X(51)X(52)X(53)X(54)X(55)X(56)X(57)X(58)X(59)X(60)X(61)X(62)X(63)

typedef const float* fp;

__device__ __forceinline__ float rlf(float v, int q){
  return __int_as_float(__builtin_amdgcn_readlane(__float_as_int(v), q));
}
__device__ __forceinline__ float fsig(float z){
  z = fminf(fmaxf(z, -30.f), 30.f);
  return 1.f / (1.f + __expf(-z));
}
__device__ __forceinline__ float ftanh(float z){
  z = fminf(fmaxf(z, -15.f), 15.f);
  float e = __expf(2.f * z);
  return (e - 1.f) / (e + 1.f);
}

// ---------------- zero scratch ----------------
__global__ void zero_kernel(float* __restrict__ p, int n){
  for (int i = blockIdx.x * blockDim.x + threadIdx.x; i < n; i += gridDim.x * blockDim.x)
    p[i] = 0.f;
}

// ---------------- embedding: x = atom_fea @ emb_W + emb_b ----------------
__global__ __launch_bounds__(256, 2) void emb_kernel(
    fp __restrict__ af, fp __restrict__ W, fp __restrict__ b,
    float* __restrict__ x)
{
  const int lane = threadIdx.x & 63, w = threadIdx.x >> 6;
#define EA(k) float wa##k = W[k * FD + lane];
  REP64(EA)
#undef EA
#define EB(k) float wb##k = W[(k + 64) * FD + lane];
  REP28(EB)
#undef EB
  const float bias = b[lane];
  const int base = blockIdx.x * 32 + w * 8;
  #pragma unroll 1
  for (int it = 0; it < 8; ++it){
    const int i = base + it;
    float ev0 = af[i * ORIGF + lane];
    float ev1 = (lane < 28) ? af[i * ORIGF + 64 + lane] : 0.f;
    float acc = bias;
#define FA(k) acc = fmaf(rlf(ev0, k), wa##k, acc);
    REP64(FA)
#undef FA
#define FB(k) acc = fmaf(rlf(ev1, k), wb##k, acc);
    REP28(FB)
#undef FB
    x[i * FD + lane] = acc;
  }
}

// ---------------- stw: out[N][128] = xin[N][64] @ W[64][128] (+bias) ----------------
__global__ __launch_bounds__(256, 4) void stw_kernel(
    const float* __restrict__ xin, fp __restrict__ W, fp __restrict__ bias,
    float* __restrict__ out)
{
  const int lane = threadIdx.x & 63, w = threadIdx.x >> 6;
  const int ch = (w & 1) * 64 + lane;
#define SW(k) float wv##k = W[k * 128 + ch];
  REP64(SW)
#undef SW
  const float bb = bias ? bias[ch] : 0.f;
  const int base = blockIdx.x * 32 + (w >> 1) * 16;
  #pragma unroll 1
  for (int it = 0; it < 16; ++it){
    const int i = base + it;
    float xv = xin[i * FD + lane];
    float acc = bb;
#define SF(k) acc = fmaf(rlf(xv, k), wv##k, acc);
    REP64(SF)
#undef SF
    out[i * 128 + ch] = acc;
  }
}

// ---------------- edge stats (fallback: no store) ----------------
__global__ __launch_bounds__(256, 2) void edge_stats_kernel(
    const float* __restrict__ S, const float* __restrict__ T,
    fp __restrict__ nbr, const int* __restrict__ idx,
    fp __restrict__ We, float* __restrict__ p1)   // p1: [NBLK][256] coalesced
{
  const int lane = threadIdx.x & 63, w = threadIdx.x >> 6;
  const int clo = lane, chi = lane + 64;
#define DW(q) float wlo##q = We[q * 128 + clo], whi##q = We[q * 128 + chi];
  REP41(DW)
#undef DW
  float sum_lo = 0.f, ssq_lo = 0.f, sum_hi = 0.f, ssq_hi = 0.f;
  const int base = blockIdx.x * 32 + w * 8;
  #pragma unroll 1
  for (int it = 0; it < 8; ++it){
    const int i = base + it;
    const float slo = S[i * 128 + clo];
    const float shi = S[i * 128 + chi];
    int kk = (lane < MN) ? idx[i * MN + lane] : 0;
    fp nb = nbr + (size_t)i * (MN * NBRF);
    int k0 = __builtin_amdgcn_readlane(kk, 0);
    float tlo = T[k0 * 128 + clo];
    float thi = T[k0 * 128 + chi];
    float ev  = (lane < NBRF) ? nb[lane] : 0.f;
    #pragma unroll 1
    for (int j = 0; j < MN; j++){
      float tlo_n = 0.f, thi_n = 0.f, ev_n = 0.f;
      if (j + 1 < MN){
        int kn = __builtin_amdgcn_readlane(kk, j + 1);
        tlo_n = T[kn * 128 + clo];
        thi_n = T[kn * 128 + chi];
        ev_n  = (lane < NBRF) ? nb[(j + 1) * NBRF + lane] : 0.f;
      }
      float glo = slo + tlo, ghi = shi + thi;
#define EF(q) { float s_ = rlf(ev, q); glo = fmaf(s_, wlo##q, glo); ghi = fmaf(s_, whi##q, ghi); }
      REP41(EF)
#undef EF
      sum_lo += glo; ssq_lo = fmaf(glo, glo, ssq_lo);
      sum_hi += ghi; ssq_hi = fmaf(ghi, ghi, ssq_hi);
      tlo = tlo_n; thi = thi_n; ev = ev_n;
    }
  }
  __shared__ float red[4 * 512];
  red[w * 512 + 2 * clo    ] = sum_lo;
  red[w * 512 + 2 * clo + 1] = ssq_lo;
  red[w * 512 + 2 * chi    ] = sum_hi;
  red[w * 512 + 2 * chi + 1] = ssq_hi;
  __syncthreads();
  const int t = threadIdx.x;            // stat id: (t>>7)*128 channels = sum|ssq
  const int ch = t & 127, which = t >> 7;
  float v = 0.f;
  #pragma unroll
  for (int ww = 0; ww < 4; ++ww) v += red[ww * 512 + 2 * ch + which];
  p1[blockIdx.x * 256 + t] = v;
}

// ---------------- edge stats + gated store (big-ws path, R10) ----------------
// Wave-split halves: waves 0,2 = ch 0..63 (16 atoms each), waves 1,3 = ch
// 64..127. e-features staged per wave in LDS (uniform ds_read broadcast, no
// readlanes); j unrolled x4 to amortize weight-register access. 41 weights +
// ~30 working regs per wave => no AGPR spill, ~6 waves/SIMD.
// gated layout PLANAR [edge][128]; each wave stores its 256B half.
__global__ __launch_bounds__(256, 4) void edge_stats_store_kernel(
    const float* __restrict__ S, const float* __restrict__ T,
    fp __restrict__ nbr, const int* __restrict__ idx,
    fp __restrict__ We, float* __restrict__ p1, float* __restrict__ gated)
{
  const int lane = threadIdx.x & 63, w = threadIdx.x >> 6;
  const int ch = (w & 1) * 64 + lane;
#define DW(q) float wv##q = We[q * 128 + ch];
  REP41(DW)
#undef DW
  __shared__ float elds[4][MN * NBRF];    // per-wave staging (sibling reads hit L2)
  float sum = 0.f, ssq = 0.f;
  const int base = blockIdx.x * 32 + (w >> 1) * 16;
  #pragma unroll 1
  for (int it = 0; it < 16; ++it){
    const int i = base + it;
    const float sv = S[i * 128 + ch];
    int kk = (lane < MN) ? idx[i * MN + lane] : 0;
    fp nb = nbr + (size_t)i * (MN * NBRF);
    // stage this atom's 12x41 edge features into LDS (coalesced)
    #pragma unroll
    for (int r = 0; r < 7; ++r) elds[w][r * 64 + lane] = nb[r * 64 + lane];
    if (lane < MN * NBRF - 448) elds[w][448 + lane] = nb[448 + lane];
    asm volatile("s_waitcnt lgkmcnt(0)" ::: "memory");   // same-wave LDS visibility
    #pragma unroll 1
    for (int jg = 0; jg < MN / 4; ++jg){
      const int j0 = jg * 4;
      int k0 = __builtin_amdgcn_readlane(kk, j0);
      int k1 = __builtin_amdgcn_readlane(kk, j0 + 1);
      int k2 = __builtin_amdgcn_readlane(kk, j0 + 2);
      int k3 = __builtin_amdgcn_readlane(kk, j0 + 3);
      float g0 = sv + T[k0 * 128 + ch];
      float g1 = sv + T[k1 * 128 + ch];
      float g2 = sv + T[k2 * 128 + ch];
      float g3 = sv + T[k3 * 128 + ch];
      const float* eb = &elds[w][j0 * NBRF];
#define EF(q) { float e0_ = eb[q]; float e1_ = eb[NBRF + q]; \
                float e2_ = eb[2 * NBRF + q]; float e3_ = eb[3 * NBRF + q]; \
                g0 = fmaf(e0_, wv##q, g0); g1 = fmaf(e1_, wv##q, g1); \
                g2 = fmaf(e2_, wv##q, g2); g3 = fmaf(e3_, wv##q, g3); }
      REP41(EF)
#undef EF
      float* gb = gated + (((size_t)(i * MN + j0)) << 7) + ch;
      gb[0]   = g0;
      gb[128] = g1;
      gb[256] = g2;
      gb[384] = g3;
      // stats in j order (bit-identical per-channel accumulation)
      sum += g0; ssq = fmaf(g0, g0, ssq);
      sum += g1; ssq = fmaf(g1, g1, ssq);
      sum += g2; ssq = fmaf(g2, g2, ssq);
      sum += g3; ssq = fmaf(g3, g3, ssq);
    }
  }
  // per-block stats: wave w holds 64 channels (half = w&1); combine waves h, h+2
  __shared__ float red[4 * 128];
  red[w * 128 + 2 * lane    ] = sum;
  red[w * 128 + 2 * lane + 1] = ssq;
  __syncthreads();
  const int t = threadIdx.x;            // which = t>>7, c = t&127 (format unchanged)
  const int c = t & 127, which = t >> 7;
  const int h = c >> 6, cl = c & 63;
  float v = red[h * 128 + 2 * cl + which] + red[(h + 2) * 128 + 2 * cl + which];
  p1[blockIdx.x * 256 + t] = v;
}

// ---------------- edge apply from stored gated (big-ws path) ----------------
// Pure stream: planar gated [edge][128]; BN1 affine, sig*tanh, sum_j.
__global__ __launch_bounds__(256, 4) void edge_apply_load_kernel(
    const float* __restrict__ gated, const float* __restrict__ ss1,
    float* __restrict__ ns, float* __restrict__ p2)   // p2: [NBLK][128]
{
  const int lane = threadIdx.x & 63, w = threadIdx.x >> 6;
  const float sc_lo = ss1[lane],      sh_lo = ss1[128 + lane];
  const float sc_hi = ss1[64 + lane], sh_hi = ss1[192 + lane];
  float sum2 = 0.f, ssq2 = 0.f;
  const int base = blockIdx.x * 32 + w * 8;
  #pragma unroll 1
  for (int it = 0; it < 8; ++it){
    const int i = base + it;
    fp gb = gated + (((size_t)i * MN) << 7);
    float acc = 0.f;
    #pragma unroll
    for (int j = 0; j < MN; ++j){
      float glo = gb[(j << 7) + lane];
      float ghi = gb[(j << 7) + 64 + lane];
      float filt = fsig(fmaf(glo, sc_lo, sh_lo));
      float core = ftanh(fmaf(ghi, sc_hi, sh_hi));
      acc = fmaf(filt, core, acc);
    }
    ns[i * FD + lane] = acc;
    sum2 += acc; ssq2 = fmaf(acc, acc, ssq2);
  }
  __shared__ float red[4 * 128];
  red[w * 128 + 2 * lane    ] = sum2;
  red[w * 128 + 2 * lane + 1] = ssq2;
  __syncthreads();
  const int t = threadIdx.x;
  if (t < 128){
    const int ch = t & 63, which = t >> 6;
    float v = 0.f;
    #pragma unroll
    for (int ww = 0; ww < 4; ++ww) v += red[ww * 128 + 2 * ch + which];
    p2[blockIdx.x * 128 + t] = v;
  }
}

// ---------------- edge apply (fallback: recompute) ----------------
__global__ __launch_bounds__(256, 2) void edge_apply_kernel(
    const float* __restrict__ S, const float* __restrict__ T,
    fp __restrict__ nbr, const int* __restrict__ idx,
    fp __restrict__ We, const float* __restrict__ ss1,
    float* __restrict__ ns, float* __restrict__ p2)   // p2: [NBLK][128]
{
  const int lane = threadIdx.x & 63, w = threadIdx.x >> 6;
  const int clo = lane, chi = lane + 64;
#define DW(q) float wlo##q = We[q * 128 + clo], whi##q = We[q * 128 + chi];
  REP41(DW)
#undef DW
  const float sc_lo = ss1[clo],       sh_lo = ss1[128 + clo];
  const float sc_hi = ss1[chi],       sh_hi = ss1[128 + chi];
  float sum2 = 0.f, ssq2 = 0.f;
  const int base = blockIdx.x * 32 + w * 8;
  #pragma unroll 1
  for (int it = 0; it < 8; ++it){
    const int i = base + it;
    const float slo = S[i * 128 + clo];
    const float shi = S[i * 128 + chi];
    int kk = (lane < MN) ? idx[i * MN + lane] : 0;
    fp nb = nbr + (size_t)i * (MN * NBRF);
    int k0 = __builtin_amdgcn_readlane(kk, 0);
    float tlo = T[k0 * 128 + clo];
    float thi = T[k0 * 128 + chi];
    float ev  = (lane < NBRF) ? nb[lane] : 0.f;
    float acc = 0.f;
    #pragma unroll 1
    for (int j = 0; j < MN; j++){
      float tlo_n = 0.f, thi_n = 0.f, ev_n = 0.f;
      if (j + 1 < MN){
        int kn = __builtin_amdgcn_readlane(kk, j + 1);
        tlo_n = T[kn * 128 + clo];
        thi_n = T[kn * 128 + chi];
        ev_n  = (lane < NBRF) ? nb[(j + 1) * NBRF + lane] : 0.f;
      }
      float glo = slo + tlo, ghi = shi + thi;
#define EF(q) { float s_ = rlf(ev, q); glo = fmaf(s_, wlo##q, glo); ghi = fmaf(s_, whi##q, ghi); }
      REP41(EF)
#undef EF
      float filt = fsig(fmaf(glo, sc_lo, sh_lo));
      float core = ftanh(fmaf(ghi, sc_hi, sh_hi));
      acc = fmaf(filt, core, acc);
      tlo = tlo_n; thi = thi_n; ev = ev_n;
    }
    ns[i * FD + lane] = acc;
    sum2 += acc; ssq2 = fmaf(acc, acc, ssq2);
  }
  __shared__ float red[4 * 128];
  red[w * 128 + 2 * lane    ] = sum2;
  red[w * 128 + 2 * lane + 1] = ssq2;
  __syncthreads();
  const int t = threadIdx.x;
  if (t < 128){
    const int ch = t & 63, which = t >> 6;
    float v = 0.f;
    #pragma unroll
    for (int ww = 0; ww < 4; ++ww) v += red[ww * 128 + 2 * ch + which];
    p2[blockIdx.x * 128 + t] = v;
  }
}

// ---------------- grid reduce of partials (coalesced rows -> atomics, 64-way) ----------------
__global__ void reduce_rows_kernel(const float* __restrict__ p, float* __restrict__ accum,
                                   int nrows, int ncols)
{
  const int t = threadIdx.x;   // blockDim.x == ncols
  float a = 0.f;
  for (int r = blockIdx.x; r < nrows; r += gridDim.x) a += p[r * ncols + t];
  atomicAdd(&accum[t], a);
}

__global__ void finalize1_kernel(const float* __restrict__ acc, fp g, fp b,
                                 float* __restrict__ ss1)
{
  const int c = threadIdx.x;   // 128
  const float inv = 1.f / 1200000.f;
  float mean = acc[c] * inv;
  float var  = fmaxf(acc[128 + c] * inv - mean * mean, 0.f);
  float sc   = g[c] * rsqrtf(var + EPSF);
  ss1[c] = sc;
  ss1[128 + c] = b[c] - mean * sc;
}

__global__ void finalize2_kernel(const float* __restrict__ acc, fp g, fp b,
                                 float* __restrict__ ss2)
{
  const int c = threadIdx.x;   // 64
  const float inv = 1.f / 100000.f;
  float mean = acc[c] * inv;
  float var  = fmaxf(acc[64 + c] * inv - mean * mean, 0.f);
  float sc   = g[c] * rsqrtf(var + EPSF);
  ss2[c] = sc;
  ss2[64 + c] = b[c] - mean * sc;
}

// ---------------- BN2 affine + residual tanh; optional f32 x output copy ----------------
__global__ __launch_bounds__(256) void bn2res_kernel(
    float* __restrict__ x, const float* __restrict__ ns,
    const float* __restrict__ ss2, float* __restrict__ xout)
{
  const int e = (blockIdx.x * 256 + threadIdx.x) * 4;   // grid sized exactly
  const int c = e & 63;
  float4 xv = *(const float4*)(x + e);
  float4 nv = *(const float4*)(ns + e);
  float r0 = ftanh(fmaf(nv.x, ss2[c + 0], ss2[64 + c + 0]) + xv.x);
  float r1 = ftanh(fmaf(nv.y, ss2[c + 1], ss2[64 + c + 1]) + xv.y);
  float r2 = ftanh(fmaf(nv.z, ss2[c + 2], ss2[64 + c + 2]) + xv.z);
  float r3 = ftanh(fmaf(nv.w, ss2[c + 3], ss2[64 + c + 3]) + xv.w);
  *(float4*)(x + e) = make_float4(r0, r1, r2, r3);
  if (xout){
    *(float4*)(xout + e) = make_float4(r0, r1, r2, r3);
  }
}

// ---------------- pooling: per-crystal sum of x + counts (sorted ids, run-accumulate) ----------------
__global__ __launch_bounds__(256) void pool1_kernel(
    const float* __restrict__ x, const int* __restrict__ cid,
    float* __restrict__ csum, float* __restrict__ ccnt)
{
  const int lane = threadIdx.x & 63, w = threadIdx.x >> 6;
  const int wg = blockIdx.x * 4 + w;
  const int i0 = wg * 64;
  if (i0 >= NA) return;
  const int i1 = min(i0 + 64, NA);
  int cur = -1; float acc = 0.f; int run = 0;
  for (int i = i0; i < i1; ++i){
    int cd = cid[i];
    if (cd != cur){
      if (cur >= 0){
        atomicAdd(&csum[cur * FD + lane], acc);
        if (lane == 0) atomicAdd(&ccnt[cur], (float)run);
      }
      cur = cd; acc = 0.f; run = 0;
    }
    acc += x[i * FD + lane];
    run++;
  }
  if (cur >= 0){
    atomicAdd(&csum[cur * FD + lane], acc);
    if (lane == 0) atomicAdd(&ccnt[cur], (float)run);
  }
}

// ---------------- c3 = tanh(crys_mean @ W3 + b3) per crystal ----------------
__global__ void cm3_kernel(const float* __restrict__ csum, const float* __restrict__ ccnt,
                           fp W3, fp b3, float* __restrict__ c3)
{
  const int b = blockIdx.x, t = threadIdx.x;   // 64 threads
  __shared__ float mean[64];
  float inv = 1.f / fmaxf(ccnt[b], 1.f);
  mean[t] = csum[b * FD + t] * inv;
  __syncthreads();
  float acc = b3[t];
  #pragma unroll
  for (int k = 0; k < 64; k++) acc = fmaf(mean[k], W3[k * FD + t], acc);
  c3[b * FD + t] = ftanh(acc);
}

// ---------------- a = sigmoid(<x_i, c3[cid]>); seg-sum of a*x ----------------
__global__ __launch_bounds__(256) void pool2_kernel(
    const float* __restrict__ x, const int* __restrict__ cid,
    const float* __restrict__ c3, float* __restrict__ cfs)
{
  const int lane = threadIdx.x & 63, w = threadIdx.x >> 6;
  const int wg = blockIdx.x * 4 + w;
  const int i0 = wg * 64;
  if (i0 >= NA) return;
  const int i1 = min(i0 + 64, NA);
  int cur = -1; float acc = 0.f;
  for (int i = i0; i < i1; ++i){
    int cd = cid[i];
    if (cd != cur){
      if (cur >= 0) atomicAdd(&cfs[cur * FD + lane], acc);
      cur = cd; acc = 0.f;
    }
    float xv = x[i * FD + lane];
    float p = xv * c3[cd * FD + lane];
    #pragma unroll
    for (int off = 32; off; off >>= 1) p += __shfl_xor(p, off);
    acc = fmaf(fsig(p), xv, acc);
  }
  if (cur >= 0) atomicAdd(&cfs[cur * FD + lane], acc);
}

// ---------------- head: softplus(mean @ fc + b) @ out_W + out_b ----------------
__global__ void head_kernel(const float* __restrict__ cfs, const float* __restrict__ ccnt,
                            fp fcW, fp fcb, fp oW, fp ob,
                            float* __restrict__ outp)
{
  const int b = blockIdx.x, t = threadIdx.x;   // 128 threads
  __shared__ float row[64];
  __shared__ float red[128];
  float inv = 1.f / fmaxf(ccnt[b], 1.f);
  if (t < 64) row[t] = cfs[b * FD + t] * inv;
  __syncthreads();
  float acc = fcb[t];
  #pragma unroll
  for (int k = 0; k < 64; k++) acc = fmaf(row[k], fcW[k * 128 + t], acc);
  float sp = (acc > 20.f) ? acc : log1pf(__expf(acc));
  red[t] = sp * oW[t];
  __syncthreads();
  for (int off = 64; off; off >>= 1){
    if (t < off) red[t] += red[t + off];
    __syncthreads();
  }
  if (t == 0) outp[b] = red[0] + ob[0];
}

// ---------------- workspace layout (floats) ----------------
static const size_t O_X    = 0;            // 6,400,000   x[N][64]
static const size_t O_S    = 6400000;      // 12,800,000  S[N][128]
static const size_t O_T    = 19200000;     // 12,800,000  T[N][128]
static const size_t O_NS   = 32000000;     // 6,400,000   nbr_sumed[N][64]
static const size_t O_P1   = 38400000;     // 800,000     [NBLK][256]
static const size_t O_P2   = 39200000;     // 400,000     [NBLK][128]
static const size_t O_SS1  = 39600000;     // 256
static const size_t O_SS2  = 39600256;     // 128
static const size_t O_G1   = 39600384;     // 256
static const size_t O_G2   = 39600640;     // 128
static const size_t O_CSUM = 39600768;     // 128,000
static const size_t O_CCNT = 39728768;     // 2,000
static const size_t O_C3   = 39730768;     // 128,000
static const size_t O_CFS  = 39858768;     // 128,000
static const size_t O_END  = 39986768;     // ~160 MB (fallback minimum)
static const size_t O_GATED= 39986768;     // 153,600,000  gated[1.2M][128]
static const size_t O_END2 = 193586768;    // ~774 MB (big path)

extern "C" void kernel_launch(void* const* d_in, const int* in_sizes, int n_in,
                              void* d_out, int out_size, void* d_ws, size_t ws_size,
                              hipStream_t stream)
{
  (void)in_sizes; (void)n_in; (void)out_size;
  if (ws_size < O_END * sizeof(float)) return;   // visible failure, no corruption
  const bool big = ws_size >= O_END2 * sizeof(float);

  fp atom_fea = (fp)d_in[0];
  fp nbr_fea  = (fp)d_in[1];
  const int* nbr_idx = (const int*)d_in[2];
  const int* cids    = (const int*)d_in[3];
  fp embW = (fp)d_in[4];
  fp embb = (fp)d_in[5];
  fp convW = (fp)d_in[6];
  fp convb = (fp)d_in[7];
  fp bn1g = (fp)d_in[8];
  fp bn1b = (fp)d_in[9];
  fp bn2g = (fp)d_in[10];
  fp bn2b = (fp)d_in[11];
  fp W3W  = (fp)d_in[12];
  fp W3b  = (fp)d_in[13];
  fp fcW  = (fp)d_in[14];
  fp fcb  = (fp)d_in[15];
  fp oW   = (fp)d_in[16];
  fp ob   = (fp)d_in[17];

  float* out_head = (float*)d_out;
  float* out_x    = out_head + NC;

  float* W  = (float*)d_ws;
  float* x    = W + O_X;
  float* S    = W + O_S;
  float* T    = W + O_T;
  float* ns   = W + O_NS;
  float* p1   = W + O_P1;
  float* p2   = W + O_P2;
  float* ss1  = W + O_SS1;
  float* ss2  = W + O_SS2;
  float* g1s  = W + O_G1;
  float* g2s  = W + O_G2;
  float* csum = W + O_CSUM;
  float* ccnt = W + O_CCNT;
  float* c3   = W + O_C3;
  float* cfs  = W + O_CFS;
  float* gated= W + O_GATED;

  // zero crystal accumulators (csum..cfs contiguous, 386,000 floats)
  zero_kernel<<<128, 256, 0, stream>>>(csum, 386000);

  emb_kernel<<<NBLK, 256, 0, stream>>>(atom_fea, embW, embb, x);

  for (int l = 0; l < 3; ++l){
    fp Wl = convW + (size_t)l * 169 * 128;
    stw_kernel<<<NBLK, 256, 0, stream>>>(x, Wl,            convb + l * 128, S);  // self rows 0..63
    stw_kernel<<<NBLK, 256, 0, stream>>>(x, Wl + 64 * 128, (fp)nullptr,     T);  // nbr rows 64..127
    zero_kernel<<<1, 256, 0, stream>>>(g1s, 384);  // g1s(256)+g2s(128) contiguous
    if (big){
      edge_stats_store_kernel<<<NBLK, 256, 0, stream>>>(S, T, nbr_fea, nbr_idx, Wl + 128 * 128, p1, gated);
      reduce_rows_kernel<<<64, 256, 0, stream>>>(p1, g1s, NBLK, 256);
      finalize1_kernel<<<1, 128, 0, stream>>>(g1s, bn1g + l * 128, bn1b + l * 128, ss1);
      edge_apply_load_kernel<<<NBLK, 256, 0, stream>>>(gated, ss1, ns, p2);
    } else {
      edge_stats_kernel<<<NBLK, 256, 0, stream>>>(S, T, nbr_fea, nbr_idx, Wl + 128 * 128, p1);
      reduce_rows_kernel<<<64, 256, 0, stream>>>(p1, g1s, NBLK, 256);
      finalize1_kernel<<<1, 128, 0, stream>>>(g1s, bn1g + l * 128, bn1b + l * 128, ss1);
      edge_apply_kernel<<<NBLK, 256, 0, stream>>>(S, T, nbr_fea, nbr_idx, Wl + 128 * 128, ss1, ns, p2);
    }
    reduce_rows_kernel<<<64, 128, 0, stream>>>(p2, g2s, NBLK, 128);
    finalize2_kernel<<<1, 64, 0, stream>>>(g2s, bn2g + l * 64, bn2b + l * 64, ss2);
    bn2res_kernel<<<6250, 256, 0, stream>>>(x, ns, ss2, (l == 2) ? out_x : (float*)nullptr);
  }

  pool1_kernel<<<391, 256, 0, stream>>>(x, cids, csum, ccnt);
  cm3_kernel<<<NC, 64, 0, stream>>>(csum, ccnt, W3W, W3b, c3);
  pool2_kernel<<<391, 256, 0, stream>>>(x, cids, c3, cfs);
  head_kernel<<<NC, 128, 0, stream>>>(cfs, ccnt, fcW, fcb, oW, ob, out_head);
}